// Round 10
// baseline (160.519 us; speedup 1.0000x reference)
//
#include <hip/hip_runtime.h>
#include <hip/hip_bf16.h>

#define N_NODES 100000
#define N_EDGES 1600000
#define HID 64

#define NG 98           // nodes per group
#define GROUPS 1021     // ceil(100000/98)
#define GSTRIDE 1024    // padded stride for counters/regions
#define NREP 2          // replica regions per group
#define RCAP 1024       // pairs per (replica,group); mean ~784, +8.5 sigma
#define EPT 16          // edges per thread in bin path (256 thr -> 4096/block)
#define BIN_BLOCKS 391  // ceil(1600000/4096)
#define LIN_BLOCKS 1563 // 6250 tiles / 4 waves per block
#define LCAP 48         // per-node src capacity; Poisson(16) P(>48) ~ 1e-11

using bf16 = __hip_bfloat16;
typedef __attribute__((ext_vector_type(8))) short short8;
typedef __attribute__((ext_vector_type(4))) float float4v;

__device__ __forceinline__ float bfbits2f(unsigned short u) {
    union { unsigned int i; float f; } v;
    v.i = ((unsigned int)u) << 16;
    return v.f;
}
__device__ __forceinline__ unsigned short f2bfbits(float f) {
    union { float f; unsigned int i; } v;
    v.f = f;
    unsigned int r = v.i + 0x7fffu + ((v.i >> 16) & 1u);  // RNE; finite inputs
    return (unsigned short)(r >> 16);
}
__device__ __forceinline__ void unpack_bf2(unsigned int u, float& lo, float& hi) {
    union { unsigned int i; float f; } a, b;
    a.i = u << 16;            // low ushort  = even feature
    b.i = u & 0xffff0000u;    // high ushort = odd feature
    lo = a.f; hi = b.f;
}

// Init: zero ALL group cursors; split W into bf16 hi/lo planes (row-major [n][k]).
__global__ __launch_bounds__(256) void k_init(
    const float* __restrict__ W, int* __restrict__ gcur,
    unsigned short* __restrict__ Whi, unsigned short* __restrict__ Wlo)
{
    const int t = blockIdx.x * 256 + threadIdx.x;
    for (int i = t; i < NREP * GSTRIDE; i += 512) gcur[i] = 0;
    for (int i = t; i < HID * HID; i += 512) {
        const float f = W[i];
        const unsigned short h = f2bfbits(f);
        Whi[i] = h;
        Wlo[i] = f2bfbits(f - bfbits2f(h));
    }
}

// Fused: blocks [0,LIN_BLOCKS) = MFMA linear (1 wave per 16-node tile, W from
// pre-split planes, 2-term split); blocks [LIN_BLOCKS,+BIN_BLOCKS) = edge binning.
__global__ __launch_bounds__(256, 4) void k_prep2(
    const float* __restrict__ x, const unsigned short* __restrict__ Whi,
    const unsigned short* __restrict__ Wlo, const float* __restrict__ b,
    bf16* __restrict__ m,
    const int* __restrict__ edges, int* __restrict__ gcur,
    int* __restrict__ binned)
{
    const int t = threadIdx.x;

    if (blockIdx.x < LIN_BLOCKS) {
        const int wv = t >> 6, l = t & 63;
        const int c = l & 15, q = l >> 4;
        const int tile = blockIdx.x * 4 + wv;
        if (tile >= N_NODES / 16) return;   // 6250 tiles cover 100k nodes exactly
        const int nb = tile * 16;

        // B[k][n] = W[n][k]: lane n = nt*16+c, k = ks*32 + q*8 + j
        const short8* whi8 = reinterpret_cast<const short8*>(Whi);
        const short8* wlo8 = reinterpret_cast<const short8*>(Wlo);
        short8 Bhi[4][2], Blo[4][2];
        #pragma unroll
        for (int nt = 0; nt < 4; ++nt)
            #pragma unroll
            for (int ks = 0; ks < 2; ++ks) {
                const int fi = (nt * 16 + c) * 8 + ks * 4 + q;
                Bhi[nt][ks] = whi8[fi];
                Blo[nt][ks] = wlo8[fi];
            }

        // A[m][k] = x[nb+m][k] rounded to bf16: lane m = c, k = ks*32 + q*8 + j
        const float* xrow = x + (size_t)(nb + c) * HID;
        short8 Ahi[2];
        #pragma unroll
        for (int ks = 0; ks < 2; ++ks)
            #pragma unroll
            for (int j = 0; j < 8; ++j)
                Ahi[ks][j] = (short)f2bfbits(xrow[ks * 32 + q * 8 + j]);

        float4v acc[4];
        #pragma unroll
        for (int nt = 0; nt < 4; ++nt) {
            const float bias = b[nt * 16 + c];
            acc[nt] = (float4v){bias, bias, bias, bias};
            #pragma unroll
            for (int ks = 0; ks < 2; ++ks) {
                acc[nt] = __builtin_amdgcn_mfma_f32_16x16x32_bf16(Ahi[ks], Bhi[nt][ks], acc[nt], 0, 0, 0);
                acc[nt] = __builtin_amdgcn_mfma_f32_16x16x32_bf16(Ahi[ks], Blo[nt][ks], acc[nt], 0, 0, 0);
            }
        }

        // C/D: col c = feature nt*16+c, row q*4+rg = node nb+q*4+rg
        unsigned short* mp = reinterpret_cast<unsigned short*>(m);
        #pragma unroll
        for (int nt = 0; nt < 4; ++nt)
            #pragma unroll
            for (int rg = 0; rg < 4; ++rg) {
                const float v = fmaxf(acc[nt][rg], 0.0f);
                mp[(size_t)(nb + q * 4 + rg) * HID + nt * 16 + c] = f2bfbits(v);
            }
    } else {
        __shared__ int cnt[GSTRIDE];
        __shared__ int base[GSTRIDE];
        const int bb = blockIdx.x - LIN_BLOCKS;
        for (int i = t; i < GSTRIDE; i += 256) cnt[i] = 0;
        __syncthreads();

        const int e0 = bb * (256 * EPT);
        int gk[EPT], pk[EPT], sl[EPT];
        #pragma unroll
        for (int k = 0; k < EPT; ++k) {
            const int e = e0 + k * 256 + t;   // coalesced per k
            if (e < N_EDGES) {
                const int dst = edges[e];             // target
                const int src = edges[N_EDGES + e];   // source
                const int g = (int)((unsigned)dst / NG);   // magic-mul div
                gk[k] = g;
                pk[k] = ((dst - g * NG) << 17) | src;  // dl(7b) | src(17b)
                sl[k] = atomicAdd(&cnt[g], 1);
            } else gk[k] = -1;
        }
        __syncthreads();
        const int r = bb & (NREP - 1);
        for (int i = t; i < GROUPS; i += 256) {
            const int cc = cnt[i];
            base[i] = cc ? atomicAdd(&gcur[r * GSTRIDE + i], cc) : 0;
        }
        __syncthreads();
        #pragma unroll
        for (int k = 0; k < EPT; ++k) {
            if (gk[k] >= 0) {
                const int pos = base[gk[k]] + sl[k];
                if ((unsigned)pos < RCAP)   // unsigned: rejects corruption too
                    binned[(size_t)(r * GSTRIDE + gk[k]) * RCAP + pos] = pk[k];
            }
        }
    }
}

// One block (512 thr, 8 waves) per 98-node group: LDS per-node src lists (int
// atomics), then one wave per node; lane (r=l>>3, c=l&7) reads 8 edge rows per
// uint4 load (1 KiB/instr over 8 random rows), all pass-loads in flight.
// 1021 blocks = 4/CU. Fused residual + RMSNorm.
__global__ __launch_bounds__(512, 8) void k_gather_norm7(
    const float* __restrict__ x, const bf16* __restrict__ m,
    const int* __restrict__ gcur, const int* __restrict__ binned,
    const float* __restrict__ nw, const float* __restrict__ nb,
    float* __restrict__ out)
{
    __shared__ int lcount[NG];
    __shared__ int lsrc[NG * LCAP];   // 19.2 KB
    const int t = threadIdx.x;
    const int g = blockIdx.x;
    for (int i = t; i < NG; i += 512) lcount[i] = 0;
    __syncthreads();

    #pragma unroll
    for (int rr = 0; rr < NREP; ++rr) {
        int cc = gcur[rr * GSTRIDE + g];
        if (cc > RCAP) cc = RCAP;
        const int* reg = binned + (size_t)(rr * GSTRIDE + g) * RCAP;
        for (int i = t; i < cc; i += 512) {
            const int pr = reg[i];
            const int dl = pr >> 17;
            const int slot = atomicAdd(&lcount[dl], 1);   // native int LDS atomic
            if (slot < LCAP) lsrc[dl * LCAP + slot] = pr & 0x1FFFF;
        }
    }
    __syncthreads();

    const int wv = t >> 6, l = t & 63;
    const int c = l & 7;      // 16B chunk: features c*8 .. c*8+7
    const int r = l >> 3;     // row-octet slot
    const uint4* mu4 = reinterpret_cast<const uint4*>(m);

    for (int dl = wv; dl < NG; dl += 8) {
        const int n = g * NG + dl;
        if (n >= N_NODES) break;
        int deg = lcount[dl]; if (deg > LCAP) deg = LCAP;   // wave-uniform
        const int* row = &lsrc[dl * LCAP];

        float a[8] = {0.f, 0.f, 0.f, 0.f, 0.f, 0.f, 0.f, 0.f};
        for (int i0 = 0; i0 < deg; i0 += 32) {
            uint4 vb[4];
            #pragma unroll
            for (int j = 0; j < 4; ++j) {       // all loads issued, then used
                const int e = i0 + j * 8 + r;
                const int ec = (e < deg) ? e : (deg - 1);
                vb[j] = mu4[(size_t)row[ec] * 8 + c];
            }
            #pragma unroll
            for (int j = 0; j < 4; ++j) {
                const int e = i0 + j * 8 + r;
                if (e < deg) {
                    float lo, hi;
                    unpack_bf2(vb[j].x, lo, hi); a[0] += lo; a[1] += hi;
                    unpack_bf2(vb[j].y, lo, hi); a[2] += lo; a[3] += hi;
                    unpack_bf2(vb[j].z, lo, hi); a[4] += lo; a[5] += hi;
                    unpack_bf2(vb[j].w, lo, hi); a[6] += lo; a[7] += hi;
                }
            }
        }
        // reduce over r (8 row-octets)
        #pragma unroll
        for (int f = 0; f < 8; ++f) {
            a[f] += __shfl_xor(a[f], 8, 64);
            a[f] += __shfl_xor(a[f], 16, 64);
            a[f] += __shfl_xor(a[f], 32, 64);
        }

        const float4 xa = reinterpret_cast<const float4*>(x)[(size_t)n * 16 + c * 2];
        const float4 xb = reinterpret_cast<const float4*>(x)[(size_t)n * 16 + c * 2 + 1];
        float h[8];
        h[0] = xa.x + a[0]; h[1] = xa.y + a[1]; h[2] = xa.z + a[2]; h[3] = xa.w + a[3];
        h[4] = xb.x + a[4]; h[5] = xb.y + a[5]; h[6] = xb.z + a[6]; h[7] = xb.w + a[7];
        float ss = 0.f;
        #pragma unroll
        for (int f = 0; f < 8; ++f) ss += h[f] * h[f];
        ss += __shfl_xor(ss, 1, 64);
        ss += __shfl_xor(ss, 2, 64);
        ss += __shfl_xor(ss, 4, 64);
        const float inv = rsqrtf(ss * (1.0f / HID) + 1e-5f);
        if (r == 0) {   // norm params loaded here to keep VGPR <= 64
            const float4 nwa = reinterpret_cast<const float4*>(nw)[c * 2];
            const float4 nwb = reinterpret_cast<const float4*>(nw)[c * 2 + 1];
            const float4 nba = reinterpret_cast<const float4*>(nb)[c * 2];
            const float4 nbb = reinterpret_cast<const float4*>(nb)[c * 2 + 1];
            float4 oa, ob;
            oa.x = nwa.x * h[0] * inv + nba.x;
            oa.y = nwa.y * h[1] * inv + nba.y;
            oa.z = nwa.z * h[2] * inv + nba.z;
            oa.w = nwa.w * h[3] * inv + nba.w;
            ob.x = nwb.x * h[4] * inv + nbb.x;
            ob.y = nwb.y * h[5] * inv + nbb.y;
            ob.z = nwb.z * h[6] * inv + nbb.z;
            ob.w = nwb.w * h[7] * inv + nbb.w;
            reinterpret_cast<float4*>(out)[(size_t)n * 16 + c * 2] = oa;
            reinterpret_cast<float4*>(out)[(size_t)n * 16 + c * 2 + 1] = ob;
        }
    }
}

extern "C" void kernel_launch(void* const* d_in, const int* in_sizes, int n_in,
                              void* d_out, int out_size, void* d_ws, size_t ws_size,
                              hipStream_t stream) {
    const float* x     = (const float*)d_in[0];
    const int*   edges = (const int*)d_in[1];
    const float* W     = (const float*)d_in[2];
    const float* b     = (const float*)d_in[3];
    const float* nw    = (const float*)d_in[4];
    const float* nb    = (const float*)d_in[5];
    float* out = (float*)d_out;

    // Workspace: gcur 8KB | Whi 8KB @16K | Wlo 8KB @24K | binned 8MB @64K | m 12.8MB
    int* gcur = (int*)d_ws;
    unsigned short* Whi = (unsigned short*)((char*)d_ws + (1 << 14));
    unsigned short* Wlo = Whi + HID * HID;
    int*  binned = (int*)((char*)d_ws + (1 << 16));
    bf16* m      = (bf16*)((char*)d_ws + (1 << 16) +
                           (size_t)NREP * GSTRIDE * RCAP * sizeof(int));

    k_init<<<2, 256, 0, stream>>>(W, gcur, Whi, Wlo);
    k_prep2<<<LIN_BLOCKS + BIN_BLOCKS, 256, 0, stream>>>(x, Whi, Wlo, b, m, edges, gcur, binned);
    k_gather_norm7<<<GROUPS, 512, 0, stream>>>(x, m, gcur, binned, nw, nb, out);
}

// Round 11
// 147.253 us; speedup vs baseline: 1.0901x; 1.0901x over previous
//
#include <hip/hip_runtime.h>
#include <hip/hip_bf16.h>

#define N_NODES 100000
#define N_EDGES 1600000
#define HID 64

#define NG 196          // nodes per group
#define GROUPS 511      // ceil(100000/196)
#define GSTRIDE 512     // padded stride for counters/regions
#define NREP 2          // replica regions per group
#define RCAP 2048       // pairs per (replica,group); mean ~1564, +12 sigma
#define EPT 16          // edges per thread in bin path (256 thr -> 4096/block)
#define BIN_BLOCKS 391  // ceil(1600000/4096)
#define LIN_BLOCKS 1563 // ceil(6250 tiles / 4 waves per block)
#define LCAP 48         // per-node src capacity; Poisson(16) P(>48) ~ 1e-11

using bf16 = __hip_bfloat16;
typedef __attribute__((ext_vector_type(8))) short short8;
typedef __attribute__((ext_vector_type(4))) float float4v;

__device__ __forceinline__ float bfbits2f(unsigned short u) {
    union { unsigned int i; float f; } v;
    v.i = ((unsigned int)u) << 16;
    return v.f;
}
__device__ __forceinline__ unsigned short f2bfbits(float f) {
    union { float f; unsigned int i; } v;
    v.f = f;
    unsigned int r = v.i + 0x7fffu + ((v.i >> 16) & 1u);  // RNE; finite inputs
    return (unsigned short)(r >> 16);
}

// Init: zero ALL group cursors; build W fragment-order planes so prep2's
// B-frag loads are lane-contiguous: Wf[((nt*2+ks)*64 + l)*8 + j] holds
// W[nt*16+(l&15)][ks*32+(l>>4)*8+j] split into bf16 hi/lo.
__global__ __launch_bounds__(256) void k_init(
    const float* __restrict__ W, int* __restrict__ gcur,
    unsigned short* __restrict__ Wfhi, unsigned short* __restrict__ Wflo)
{
    const int t = blockIdx.x * 256 + threadIdx.x;
    for (int i = t; i < NREP * GSTRIDE; i += 512) gcur[i] = 0;
    for (int o = t; o < HID * HID; o += 512) {
        const int j = o & 7, l = (o >> 3) & 63, ksnt = o >> 9;
        const int ks = ksnt & 1, nt = ksnt >> 1;
        const int c = l & 15, q = l >> 4;
        const float f = W[(size_t)(nt * 16 + c) * HID + ks * 32 + q * 8 + j];
        const unsigned short h = f2bfbits(f);
        Wfhi[o] = h;
        Wflo[o] = f2bfbits(f - bfbits2f(h));
    }
}

// Fused: blocks [0,LIN_BLOCKS) = MFMA linear (4 waves x one 16-node tile each;
// x staged via LDS so global reads are coalesced; W-frags from pre-swizzled
// planes so B loads are lane-contiguous). Blocks [LIN_BLOCKS,...) = binning.
__global__ __launch_bounds__(256, 4) void k_prep2(
    const float* __restrict__ x, const unsigned short* __restrict__ Wfhi,
    const unsigned short* __restrict__ Wflo, const float* __restrict__ b,
    bf16* __restrict__ m,
    const int* __restrict__ edges, int* __restrict__ gcur,
    int* __restrict__ binned)
{
    __shared__ union SM {
        struct { float xs[64 * 65]; } lin;                    // 16.6 KB, pad 65
        struct { int cnt[GSTRIDE]; int base[GSTRIDE]; } bin;  // 4 KB
    } sm;
    const int t = threadIdx.x;

    if (blockIdx.x < LIN_BLOCKS) {
        // Stage 64 node rows coalesced into LDS (padded stride 65).
        const int nb0 = blockIdx.x * 64;
        const float4* xg = reinterpret_cast<const float4*>(x) + (size_t)nb0 * 16;
        #pragma unroll
        for (int k = 0; k < 4; ++k) {
            const int f4 = t + k * 256;                 // float4 idx within block
            float4 v = make_float4(0.f, 0.f, 0.f, 0.f);
            if (nb0 * 16 + f4 < N_NODES * 16) v = xg[f4];
            const int r = f4 >> 4, fc = (f4 & 15) * 4;
            float* dst = &sm.lin.xs[r * 65 + fc];
            dst[0] = v.x; dst[1] = v.y; dst[2] = v.z; dst[3] = v.w;
        }
        __syncthreads();

        const int wv = t >> 6, l = t & 63;
        const int c = l & 15, q = l >> 4;
        const int tile = blockIdx.x * 4 + wv;
        if (tile >= N_NODES / 16) return;   // 6250 tiles cover 100k nodes exactly
        const int nb = tile * 16;

        // B-frags: lane-contiguous loads from pre-swizzled planes.
        const short8* wfh = reinterpret_cast<const short8*>(Wfhi);
        const short8* wfl = reinterpret_cast<const short8*>(Wflo);
        short8 Bhi[4][2], Blo[4][2];
        #pragma unroll
        for (int nt = 0; nt < 4; ++nt)
            #pragma unroll
            for (int ks = 0; ks < 2; ++ks) {
                const int fi = (nt * 2 + ks) * 64 + l;
                Bhi[nt][ks] = wfh[fi];
                Blo[nt][ks] = wfl[fi];
            }

        // A-frags from LDS (bank-conflict-free via pad), bf16 RNE convert.
        short8 Ahi[2];
        #pragma unroll
        for (int ks = 0; ks < 2; ++ks) {
            const float* xsrc = &sm.lin.xs[(wv * 16 + c) * 65 + ks * 32 + q * 8];
            #pragma unroll
            for (int j = 0; j < 8; ++j)
                Ahi[ks][j] = (short)f2bfbits(xsrc[j]);
        }

        float4v acc[4];
        #pragma unroll
        for (int nt = 0; nt < 4; ++nt) {
            const float bias = b[nt * 16 + c];
            acc[nt] = (float4v){bias, bias, bias, bias};
            #pragma unroll
            for (int ks = 0; ks < 2; ++ks) {
                acc[nt] = __builtin_amdgcn_mfma_f32_16x16x32_bf16(Ahi[ks], Bhi[nt][ks], acc[nt], 0, 0, 0);
                acc[nt] = __builtin_amdgcn_mfma_f32_16x16x32_bf16(Ahi[ks], Blo[nt][ks], acc[nt], 0, 0, 0);
            }
        }

        // C/D: col c = feature nt*16+c, row q*4+rg = node nb+q*4+rg
        unsigned short* mp = reinterpret_cast<unsigned short*>(m);
        #pragma unroll
        for (int nt = 0; nt < 4; ++nt)
            #pragma unroll
            for (int rg = 0; rg < 4; ++rg) {
                const float v = fmaxf(acc[nt][rg], 0.0f);
                mp[(size_t)(nb + q * 4 + rg) * HID + nt * 16 + c] = f2bfbits(v);
            }
    } else {
        int* cnt  = sm.bin.cnt;
        int* base = sm.bin.base;
        const int bb = blockIdx.x - LIN_BLOCKS;
        for (int i = t; i < GSTRIDE; i += 256) cnt[i] = 0;
        __syncthreads();

        const int e0 = bb * (256 * EPT);
        int gk[EPT], pk[EPT], sl[EPT];
        #pragma unroll
        for (int k = 0; k < EPT; ++k) {
            const int e = e0 + k * 256 + t;   // coalesced per k
            if (e < N_EDGES) {
                const int dst = edges[e];             // target
                const int src = edges[N_EDGES + e];   // source
                const int g = (int)((unsigned)dst / NG);   // magic-mul div
                gk[k] = g;
                pk[k] = ((dst - g * NG) << 17) | src;  // dl(8b) | src(17b)
                sl[k] = atomicAdd(&cnt[g], 1);
            } else gk[k] = -1;
        }
        __syncthreads();
        const int r = bb & (NREP - 1);
        for (int i = t; i < GROUPS; i += 256) {
            const int cc = cnt[i];
            base[i] = cc ? atomicAdd(&gcur[r * GSTRIDE + i], cc) : 0;
        }
        __syncthreads();
        #pragma unroll
        for (int k = 0; k < EPT; ++k) {
            if (gk[k] >= 0) {
                const int pos = base[gk[k]] + sl[k];
                if ((unsigned)pos < RCAP)   // unsigned: rejects corruption too
                    binned[(size_t)(r * GSTRIDE + gk[k]) * RCAP + pos] = pk[k];
            }
        }
    }
}

// R9's gather6 (measured 44.1 us): one block (1024 thr) per 196-node group,
// LDS per-node src lists (int atomics), one wave per node, all row-loads of a
// pass in flight (ushort4 over 4 rows), fused residual + RMSNorm.
__global__ __launch_bounds__(1024, 8) void k_gather_norm6(
    const float* __restrict__ x, const bf16* __restrict__ m,
    const int* __restrict__ gcur, const int* __restrict__ binned,
    const float* __restrict__ nw, const float* __restrict__ nb,
    float* __restrict__ out)
{
    __shared__ int lcount[NG];
    __shared__ int lsrc[NG * LCAP];   // 37.6 KB
    const int t = threadIdx.x;
    const int g = blockIdx.x;
    for (int i = t; i < NG; i += 1024) lcount[i] = 0;
    __syncthreads();

    #pragma unroll
    for (int rr = 0; rr < NREP; ++rr) {
        int c = gcur[rr * GSTRIDE + g];
        if (c > RCAP) c = RCAP;
        const int* reg = binned + (size_t)(rr * GSTRIDE + g) * RCAP;
        for (int i = t; i < c; i += 1024) {
            const int pr = reg[i];
            const int dl = pr >> 17;
            const int slot = atomicAdd(&lcount[dl], 1);   // native int LDS atomic
            if (slot < LCAP) lsrc[dl * LCAP + slot] = pr & 0x1FFFF;
        }
    }
    __syncthreads();

    const int wv = t >> 6, l = t & 63;
    const int c = l & 15;      // feature quad: features c*4 .. c*4+3
    const int r = l >> 4;      // row slot within a 4-row group
    const ushort4* mu4 = reinterpret_cast<const ushort4*>(m);
    const float4 nw4 = reinterpret_cast<const float4*>(nw)[c];
    const float4 nb4 = reinterpret_cast<const float4*>(nb)[c];

    for (int dl = wv; dl < NG; dl += 16) {
        const int n = g * NG + dl;
        if (n >= N_NODES) break;
        int deg = lcount[dl]; if (deg > LCAP) deg = LCAP;   // wave-uniform
        const int* row = &lsrc[dl * LCAP];

        float4 a = make_float4(0.f, 0.f, 0.f, 0.f);
        for (int i0 = 0; i0 < deg; i0 += 32) {
            ushort4 vb[8];
            #pragma unroll
            for (int j = 0; j < 8; ++j) {          // all loads issued, then used
                const int e = i0 + j * 4 + r;
                const int ec = (e < deg) ? e : (deg - 1);
                vb[j] = mu4[(size_t)row[ec] * 16 + c];
            }
            #pragma unroll
            for (int j = 0; j < 8; ++j) {
                const int e = i0 + j * 4 + r;
                if (e < deg) {
                    a.x += bfbits2f(vb[j].x);
                    a.y += bfbits2f(vb[j].y);
                    a.z += bfbits2f(vb[j].z);
                    a.w += bfbits2f(vb[j].w);
                }
            }
        }
        // reduce over r (4 row-groups)
        a.x += __shfl_xor(a.x, 16, 64); a.x += __shfl_xor(a.x, 32, 64);
        a.y += __shfl_xor(a.y, 16, 64); a.y += __shfl_xor(a.y, 32, 64);
        a.z += __shfl_xor(a.z, 16, 64); a.z += __shfl_xor(a.z, 32, 64);
        a.w += __shfl_xor(a.w, 16, 64); a.w += __shfl_xor(a.w, 32, 64);

        const float4 x4 = reinterpret_cast<const float4*>(x)[(size_t)n * 16 + c];
        float4 h;
        h.x = x4.x + a.x; h.y = x4.y + a.y; h.z = x4.z + a.z; h.w = x4.w + a.w;
        float ss = h.x * h.x + h.y * h.y + h.z * h.z + h.w * h.w;
        ss += __shfl_xor(ss, 1, 64);
        ss += __shfl_xor(ss, 2, 64);
        ss += __shfl_xor(ss, 4, 64);
        ss += __shfl_xor(ss, 8, 64);
        const float inv = rsqrtf(ss * (1.0f / HID) + 1e-5f);
        if (r == 0) {
            float4 o;
            o.x = nw4.x * h.x * inv + nb4.x;
            o.y = nw4.y * h.y * inv + nb4.y;
            o.z = nw4.z * h.z * inv + nb4.z;
            o.w = nw4.w * h.w * inv + nb4.w;
            reinterpret_cast<float4*>(out)[(size_t)n * 16 + c] = o;
        }
    }
}

extern "C" void kernel_launch(void* const* d_in, const int* in_sizes, int n_in,
                              void* d_out, int out_size, void* d_ws, size_t ws_size,
                              hipStream_t stream) {
    const float* x     = (const float*)d_in[0];
    const int*   edges = (const int*)d_in[1];
    const float* W     = (const float*)d_in[2];
    const float* b     = (const float*)d_in[3];
    const float* nw    = (const float*)d_in[4];
    const float* nb    = (const float*)d_in[5];
    float* out = (float*)d_out;

    // Workspace: gcur 4KB | Wfhi 8KB @16K | Wflo 8KB @24K | binned 8MB @64K | m 12.8MB
    int* gcur = (int*)d_ws;
    unsigned short* Wfhi = (unsigned short*)((char*)d_ws + (1 << 14));
    unsigned short* Wflo = Wfhi + HID * HID;
    int*  binned = (int*)((char*)d_ws + (1 << 16));
    bf16* m      = (bf16*)((char*)d_ws + (1 << 16) +
                           (size_t)NREP * GSTRIDE * RCAP * sizeof(int));

    k_init<<<2, 256, 0, stream>>>(W, gcur, Wfhi, Wflo);
    k_prep2<<<LIN_BLOCKS + BIN_BLOCKS, 256, 0, stream>>>(x, Wfhi, Wflo, b, m, edges, gcur, binned);
    k_gather_norm6<<<GROUPS, 1024, 0, stream>>>(x, m, gcur, binned, nw, nb, out);
}